// Round 16
// baseline (385.346 us; speedup 1.0000x reference)
//
#include <hip/hip_runtime.h>

#define N_NODES_C 100000
#define N_EDGES_C 1600000
#define IN_F 64
#define OUT_F 64
#define NK 4
#define SCAN_BLK 256
#define NBLK ((N_NODES_C + SCAN_BLK - 1) / SCAN_BLK)   // 391
#define EBLK (N_EDGES_C / 256)                         // 6250 exact
#define CPAD 16                                        // cursor stride: 1 per 64B line
#define NSLICE 8
#define SLICE_N (N_NODES_C / NSLICE)                   // 12500 exact
#define BCAP 204800                                    // mean 200K + 11 sigma
#define SLICE_GRID 2048                                // 256 blocks per slice
#define SLICE_W 65536                                  // workers per slice (256*256)

__device__ __forceinline__ unsigned int f2bf(float x) {
    unsigned int u = __float_as_uint(x);
    return (u + 0x7fffu + ((u >> 16) & 1u)) >> 16;
}
__device__ __forceinline__ float bflo(unsigned int u) { return __uint_as_float(u << 16); }
__device__ __forceinline__ float bfhi(unsigned int u) { return __uint_as_float(u & 0xffff0000u); }

// ---------------------------------------------------------------------------
// binA: per-block 8-bin histogram of dst slices -> cnt8[chunk][8]
// ---------------------------------------------------------------------------
__global__ __launch_bounds__(256) void binA_kernel(
    const int* __restrict__ dst, int* __restrict__ cnt8)
{
    __shared__ int lcnt[NSLICE];
    const int t = threadIdx.x;
    if (t < NSLICE) lcnt[t] = 0;
    __syncthreads();
    const int s8 = dst[blockIdx.x * 256 + t] / SLICE_N;
    atomicAdd(&lcnt[s8], 1);
    __syncthreads();
    if (t < NSLICE) cnt8[blockIdx.x * NSLICE + t] = lcnt[t];
}

// ---------------------------------------------------------------------------
// binscan: 8 blocks; block s converts cnt8[:,s] counts -> exclusive offsets,
// writes totals[s].
// ---------------------------------------------------------------------------
__global__ __launch_bounds__(256) void binscan_kernel(
    int* __restrict__ cnt8, int* __restrict__ totals)
{
    __shared__ int sh[256];
    const int s = blockIdx.x;
    const int t = threadIdx.x;
    int running = 0;
    for (int c = 0; c < (EBLK + 255) / 256; ++c) {
        const int idx = c * 256 + t;
        int v = (idx < EBLK) ? cnt8[idx * NSLICE + s] : 0;
        sh[t] = v; __syncthreads();
        for (int off = 1; off < 256; off <<= 1) {
            int x = (t >= off) ? sh[t - off] : 0;
            __syncthreads();
            sh[t] += x;
            __syncthreads();
        }
        if (idx < EBLK) cnt8[idx * NSLICE + s] = sh[t] - v + running;  // exclusive
        running += sh[255];
        __syncthreads();
    }
    if (t == 0) totals[s] = running;
}

// ---------------------------------------------------------------------------
// binB: write {e, dst} into slice bins (deterministic, LDS ranks)
// ---------------------------------------------------------------------------
__global__ __launch_bounds__(256) void binB_kernel(
    const int* __restrict__ dst, const int* __restrict__ cnt8,
    uint2* __restrict__ binbuf)
{
    __shared__ int lcnt[NSLICE];
    const int t = threadIdx.x;
    if (t < NSLICE) lcnt[t] = 0;
    __syncthreads();
    const int e = blockIdx.x * 256 + t;
    const int d = dst[e];
    const int s8 = d / SLICE_N;
    const int rank = atomicAdd(&lcnt[s8], 1);
    const int pos = cnt8[blockIdx.x * NSLICE + s8] + rank;
    uint2 r; r.x = (unsigned int)e; r.y = (unsigned int)d;
    binbuf[(size_t)s8 * BCAP + pos] = r;
}

// ---------------------------------------------------------------------------
// hist: block b -> slice b&7; coalesced bin read, all lanes active,
// XCD-local cnt atomics.
// ---------------------------------------------------------------------------
__global__ __launch_bounds__(256) void hist_kernel(
    const uint2* __restrict__ binbuf, const int* __restrict__ totals,
    int* __restrict__ cnt)
{
    const int slice = (int)blockIdx.x & 7;
    const int wid = (((int)blockIdx.x >> 3) << 8) + (int)threadIdx.x;  // 0..65535
    const int n = totals[slice];
    const uint2* bin = binbuf + (size_t)slice * BCAP;
    for (int i = wid; i < n; i += SLICE_W)
        atomicAdd(&cnt[bin[i].y], 1);
}

// ---------------------------------------------------------------------------
// proj: 4 nodes/iter, float4 LDS reads, scalar wreg[64] (proven structure)
// ---------------------------------------------------------------------------
__global__ __launch_bounds__(256, 2) void proj_kernel(
    const float* __restrict__ feat, const float* __restrict__ W,
    unsigned short* __restrict__ hb, int n_nodes)
{
    __shared__ float frow[4][IN_F];
    const int t = threadIdx.x;
    const int o = t >> 2;
    const int k = t & 3;
    float wreg[IN_F];
    {
        const float4* W4 = reinterpret_cast<const float4*>(W + (size_t)(k * OUT_F + o) * IN_F);
        #pragma unroll
        for (int i = 0; i < IN_F / 4; ++i) {
            float4 v = W4[i];
            wreg[4*i+0] = v.x; wreg[4*i+1] = v.y; wreg[4*i+2] = v.z; wreg[4*i+3] = v.w;
        }
    }
    const int nn4 = n_nodes >> 2;   // 25000
    for (int q = blockIdx.x; q < nn4; q += gridDim.x) {
        const int n0 = q << 2;
        if (t < 64) {
            float4 v = reinterpret_cast<const float4*>(feat + (size_t)n0 * IN_F)[t];
            reinterpret_cast<float4*>(frow[t >> 4])[t & 15] = v;
        }
        __syncthreads();
        const float4* f0 = reinterpret_cast<const float4*>(frow[0]);
        const float4* f1 = reinterpret_cast<const float4*>(frow[1]);
        const float4* f2 = reinterpret_cast<const float4*>(frow[2]);
        const float4* f3 = reinterpret_cast<const float4*>(frow[3]);
        float a0 = 0.f, a1 = 0.f, a2 = 0.f, a3 = 0.f;
        #pragma unroll
        for (int i = 0; i < IN_F / 4; ++i) {
            const float4 v0 = f0[i], v1 = f1[i], v2 = f2[i], v3 = f3[i];
            const float w0 = wreg[4*i], w1 = wreg[4*i+1], w2 = wreg[4*i+2], w3 = wreg[4*i+3];
            a0 = fmaf(v0.x,w0, fmaf(v0.y,w1, fmaf(v0.z,w2, fmaf(v0.w,w3, a0))));
            a1 = fmaf(v1.x,w0, fmaf(v1.y,w1, fmaf(v1.z,w2, fmaf(v1.w,w3, a1))));
            a2 = fmaf(v2.x,w0, fmaf(v2.y,w1, fmaf(v2.z,w2, fmaf(v2.w,w3, a2))));
            a3 = fmaf(v3.x,w0, fmaf(v3.y,w1, fmaf(v3.z,w2, fmaf(v3.w,w3, a3))));
        }
        hb[(size_t)(n0+0) * 256 + t] = (unsigned short)f2bf(a0);
        hb[(size_t)(n0+1) * 256 + t] = (unsigned short)f2bf(a1);
        hb[(size_t)(n0+2) * 256 + t] = (unsigned short)f2bf(a2);
        hb[(size_t)(n0+3) * 256 + t] = (unsigned short)f2bf(a3);
        __syncthreads();
    }
}

// ---------------------------------------------------------------------------
// scan1: per-block sums of cnt
// ---------------------------------------------------------------------------
__global__ __launch_bounds__(256) void scan1_kernel(
    const int* __restrict__ cnt, int* __restrict__ bsum)
{
    __shared__ int s[SCAN_BLK];
    int i = blockIdx.x * SCAN_BLK + threadIdx.x;
    int v = (i < N_NODES_C) ? cnt[i] : 0;
    s[threadIdx.x] = v; __syncthreads();
    for (int off = SCAN_BLK / 2; off > 0; off >>= 1) {
        if (threadIdx.x < off) s[threadIdx.x] += s[threadIdx.x + off];
        __syncthreads();
    }
    if (threadIdx.x == 0) bsum[blockIdx.x] = s[0];
}

// ---------------------------------------------------------------------------
// scan23: block-prefix over bsum + local exclusive scan -> row_start,
// padded cursor
// ---------------------------------------------------------------------------
__global__ __launch_bounds__(256) void scan23_kernel(
    const int* __restrict__ cnt, const int* __restrict__ bsum,
    int* __restrict__ row_start, int* __restrict__ cursor_pad)
{
    __shared__ int pre[SCAN_BLK];
    __shared__ int s[SCAN_BLK];
    const int t = threadIdx.x;
    int p = 0;
    for (int i = t; i < (int)blockIdx.x; i += SCAN_BLK) p += bsum[i];
    pre[t] = p; __syncthreads();
    for (int off = SCAN_BLK / 2; off > 0; off >>= 1) {
        if (t < off) pre[t] += pre[t + off];
        __syncthreads();
    }
    const int boff = pre[0];
    const int i = blockIdx.x * SCAN_BLK + t;
    int v = (i < N_NODES_C) ? cnt[i] : 0;
    s[t] = v; __syncthreads();
    for (int off = 1; off < SCAN_BLK; off <<= 1) {
        int x = (t >= off) ? s[t - off] : 0;
        __syncthreads();
        s[t] += x;
        __syncthreads();
    }
    if (i < N_NODES_C) {
        int ex = s[t] - v + boff;
        row_start[i] = ex;
        cursor_pad[(size_t)i * CPAD] = ex;
        if (i == N_NODES_C - 1) row_start[N_NODES_C] = ex + v;
    }
}

// ---------------------------------------------------------------------------
// scatter: block b -> slice b&7; coalesced bin read, ALL lanes active,
// gauss computed once per edge, XCD-local cursor atomic + rec store.
// ---------------------------------------------------------------------------
__global__ __launch_bounds__(256) void scatter_kernel(
    const uint2* __restrict__ binbuf, const int* __restrict__ totals,
    const int* __restrict__ src, const float* __restrict__ pseudo,
    const float* __restrict__ mu, const float* __restrict__ inv_sigma,
    int* __restrict__ cursor_pad, uint4* __restrict__ rec)
{
    float mm[NK*3], ss[NK*3];
    #pragma unroll
    for (int i = 0; i < NK*3; ++i) { mm[i] = mu[i]; ss[i] = inv_sigma[i]; }
    const int slice = (int)blockIdx.x & 7;
    const int wid = (((int)blockIdx.x >> 3) << 8) + (int)threadIdx.x;  // 0..65535
    const int n = totals[slice];
    const uint2* bin = binbuf + (size_t)slice * BCAP;
    for (int i = wid; i < n; i += SLICE_W) {
        const uint2 ed = bin[i];
        const int e = (int)ed.x;
        const int d = (int)ed.y;
        const float p0 = pseudo[(size_t)e * 3 + 0];
        const float p1 = pseudo[(size_t)e * 3 + 1];
        const float p2 = pseudo[(size_t)e * 3 + 2];
        float g[NK];
        #pragma unroll
        for (int k = 0; k < NK; ++k) {
            const float d0 = p0 - mm[k*3+0], d1 = p1 - mm[k*3+1], d2 = p2 - mm[k*3+2];
            const float s0 = ss[k*3+0], s1 = ss[k*3+1], s2 = ss[k*3+2];
            g[k] = __expf(-0.5f * (d0*d0*s0*s0 + d1*d1*s1*s1 + d2*d2*s2*s2));
        }
        const int pos = atomicAdd(&cursor_pad[(size_t)d * CPAD], 1);
        uint4 r;
        r.x = (unsigned int)src[e];
        r.y = f2bf(g[0]) | (f2bf(g[1]) << 16);
        r.z = f2bf(g[2]) | (f2bf(g[3]) << 16);
        r.w = 0u;
        rec[pos] = r;
    }
}

// ---------------------------------------------------------------------------
// gather: one wave per dst node (R14 pipelined version, at structural floor)
// ---------------------------------------------------------------------------
__global__ __launch_bounds__(256, 2) void gather_kernel(
    const int* __restrict__ row_start, const uint4* __restrict__ rec,
    const unsigned short* __restrict__ hb,
    const float* __restrict__ feat, const float* __restrict__ bias,
    float* __restrict__ out, int n_nodes)
{
    const int lane = threadIdx.x & 63;
    const int v = (blockIdx.x * 256 + threadIdx.x) >> 6;
    if (v >= n_nodes) return;
    const int r0 = row_start[v];
    const int r1 = row_start[v + 1];
    float acc = 0.f;
    int j = r0;
    const int jend4 = r0 + ((r1 - r0) & ~3);
    if (j < jend4) {
        uint4 a0 = rec[j+0], a1 = rec[j+1], a2 = rec[j+2], a3 = rec[j+3];
        j += 4;
        for (; j < jend4; j += 4) {
            const uint2 h0 = *(const uint2*)(hb + (size_t)a0.x * 256 + lane * 4);
            const uint2 h1 = *(const uint2*)(hb + (size_t)a1.x * 256 + lane * 4);
            const uint2 h2 = *(const uint2*)(hb + (size_t)a2.x * 256 + lane * 4);
            const uint2 h3 = *(const uint2*)(hb + (size_t)a3.x * 256 + lane * 4);
            const uint4 b0 = rec[j+0], b1 = rec[j+1], b2 = rec[j+2], b3 = rec[j+3];
            acc += bflo(a0.y)*bflo(h0.x) + bfhi(a0.y)*bfhi(h0.x)
                 + bflo(a0.z)*bflo(h0.y) + bfhi(a0.z)*bfhi(h0.y);
            acc += bflo(a1.y)*bflo(h1.x) + bfhi(a1.y)*bfhi(h1.x)
                 + bflo(a1.z)*bflo(h1.y) + bfhi(a1.z)*bfhi(h1.y);
            acc += bflo(a2.y)*bflo(h2.x) + bfhi(a2.y)*bfhi(h2.x)
                 + bflo(a2.z)*bflo(h2.y) + bfhi(a2.z)*bfhi(h2.y);
            acc += bflo(a3.y)*bflo(h3.x) + bfhi(a3.y)*bfhi(h3.x)
                 + bflo(a3.z)*bflo(h3.y) + bfhi(a3.z)*bfhi(h3.y);
            a0 = b0; a1 = b1; a2 = b2; a3 = b3;
        }
        {
            const uint2 h0 = *(const uint2*)(hb + (size_t)a0.x * 256 + lane * 4);
            const uint2 h1 = *(const uint2*)(hb + (size_t)a1.x * 256 + lane * 4);
            const uint2 h2 = *(const uint2*)(hb + (size_t)a2.x * 256 + lane * 4);
            const uint2 h3 = *(const uint2*)(hb + (size_t)a3.x * 256 + lane * 4);
            acc += bflo(a0.y)*bflo(h0.x) + bfhi(a0.y)*bfhi(h0.x)
                 + bflo(a0.z)*bflo(h0.y) + bfhi(a0.z)*bfhi(h0.y);
            acc += bflo(a1.y)*bflo(h1.x) + bfhi(a1.y)*bfhi(h1.x)
                 + bflo(a1.z)*bflo(h1.y) + bfhi(a1.z)*bfhi(h1.y);
            acc += bflo(a2.y)*bflo(h2.x) + bfhi(a2.y)*bfhi(h2.x)
                 + bflo(a2.z)*bflo(h2.y) + bfhi(a2.z)*bfhi(h2.y);
            acc += bflo(a3.y)*bflo(h3.x) + bfhi(a3.y)*bfhi(h3.x)
                 + bflo(a3.z)*bflo(h3.y) + bfhi(a3.z)*bfhi(h3.y);
        }
    }
    for (; j < r1; ++j) {
        const uint4 ra = rec[j];
        const uint2 ha = *(const uint2*)(hb + (size_t)ra.x * 256 + lane * 4);
        acc += bflo(ra.y)*bflo(ha.x) + bfhi(ra.y)*bfhi(ha.x)
             + bflo(ra.z)*bflo(ha.y) + bfhi(ra.z)*bfhi(ha.y);
    }
    out[(size_t)v * OUT_F + lane] = acc + feat[(size_t)v * OUT_F + lane] + bias[lane];
}

extern "C" void kernel_launch(void* const* d_in, const int* in_sizes, int n_in,
                              void* d_out, int out_size, void* d_ws, size_t ws_size,
                              hipStream_t stream) {
    const float* feat      = (const float*)d_in[0];
    const float* pseudo    = (const float*)d_in[1];
    const int*   src       = (const int*)d_in[2];
    const int*   dst       = (const int*)d_in[3];
    const float* W_fc      = (const float*)d_in[4];
    const float* mu        = (const float*)d_in[5];
    const float* inv_sigma = (const float*)d_in[6];
    const float* bias      = (const float*)d_in[7];
    float* out = (float*)d_out;

    char* ws = (char*)d_ws;
    unsigned short* hb = (unsigned short*)ws;  ws += (size_t)N_NODES_C * 256 * 2;     // 51.2 MB
    uint4* rec         = (uint4*)ws;           ws += (size_t)N_EDGES_C * 16;          // 25.6 MB
    uint2* binbuf      = (uint2*)ws;           ws += (size_t)NSLICE * BCAP * 8;       // 13.1 MB
    int* cursor_pad    = (int*)ws;             ws += (size_t)N_NODES_C * CPAD * 4;    // 6.4 MB
    int* cnt           = (int*)ws;             ws += (size_t)N_NODES_C * 4;           // 0.4 MB
    int* row_start     = (int*)ws;             ws += (size_t)(N_NODES_C + 4) * 4;     // 0.4 MB
    int* cnt8          = (int*)ws;             ws += (size_t)EBLK * NSLICE * 4;       // 0.2 MB
    int* bsum          = (int*)ws;             ws += 512 * 4;
    int* totals        = (int*)ws;             ws += 64 * 4;

    hipMemsetAsync(cnt, 0, (size_t)N_NODES_C * 4, stream);
    binA_kernel<<<EBLK, 256, 0, stream>>>(dst, cnt8);
    binscan_kernel<<<NSLICE, 256, 0, stream>>>(cnt8, totals);
    binB_kernel<<<EBLK, 256, 0, stream>>>(dst, cnt8, binbuf);
    hist_kernel<<<SLICE_GRID, 256, 0, stream>>>(binbuf, totals, cnt);
    proj_kernel<<<2048, 256, 0, stream>>>(feat, W_fc, hb, N_NODES_C);
    scan1_kernel<<<NBLK, SCAN_BLK, 0, stream>>>(cnt, bsum);
    scan23_kernel<<<NBLK, SCAN_BLK, 0, stream>>>(cnt, bsum, row_start, cursor_pad);
    scatter_kernel<<<SLICE_GRID, 256, 0, stream>>>(binbuf, totals, src, pseudo,
                                                   mu, inv_sigma, cursor_pad, rec);
    gather_kernel<<<(N_NODES_C * 64 + 255) / 256, 256, 0, stream>>>(
        row_start, rec, hb, feat, bias, out, N_NODES_C);
}

// Round 17
// 331.256 us; speedup vs baseline: 1.1633x; 1.1633x over previous
//
#include <hip/hip_runtime.h>

#define N_NODES_C 100000
#define N_EDGES_C 1600000
#define IN_F 64
#define OUT_F 64
#define NK 4
#define SCAN_BLK 256
#define NBLK ((N_NODES_C + SCAN_BLK - 1) / SCAN_BLK)   // 391
#define EBLK (N_EDGES_C / 256)                         // 6250 exact
#define CPAD 16                                        // cursor stride: 1 per 64B line
#define NSLICE 8
#define SLICE_N (N_NODES_C / NSLICE)                   // 12500 exact
#define SCAT_GRID 2048                                 // 256 blocks per slice

__device__ __forceinline__ unsigned int f2bf(float x) {
    unsigned int u = __float_as_uint(x);
    return (u + 0x7fffu + ((u >> 16) & 1u)) >> 16;
}
__device__ __forceinline__ float bflo(unsigned int u) { return __uint_as_float(u << 16); }
__device__ __forceinline__ float bfhi(unsigned int u) { return __uint_as_float(u & 0xffff0000u); }

// ---------------------------------------------------------------------------
// proj_hist: sequential phases in ONE kernel (saves a launch + overlaps).
// Phase A: XCD-sliced hist (block b counts dst-slice b&7 -> cnt atomics local).
// Phase B: proj, 4 nodes/iter, float4 LDS reads, scalar wreg[64].
// NOT a per-block role branch (R5-R7 lesson): every block runs both phases,
// so regalloc sizes for the fat phase (~64 VGPR) and hist can't shrink it.
// ---------------------------------------------------------------------------
__global__ __launch_bounds__(256, 2) void proj_hist_kernel(
    const int* __restrict__ dst, int* __restrict__ cnt,
    const float* __restrict__ feat, const float* __restrict__ W,
    unsigned short* __restrict__ hb, int n_nodes)
{
    // ---- Phase A: sliced histogram ----
    {
        const int slice = (int)blockIdx.x & 7;
        const int w     = (int)blockIdx.x >> 3;          // 0..255 within slice
        const int lo = slice * SLICE_N, hi = lo + SLICE_N;
        for (int c = w; c < EBLK; c += SCAT_GRID / NSLICE) {
            const int d = dst[c * 256 + (int)threadIdx.x];
            if (d >= lo && d < hi) atomicAdd(&cnt[d], 1);
        }
    }
    // ---- Phase B: projection ----
    __shared__ float frow[4][IN_F];
    const int t = threadIdx.x;
    const int o = t >> 2;
    const int k = t & 3;
    float wreg[IN_F];
    {
        const float4* W4 = reinterpret_cast<const float4*>(W + (size_t)(k * OUT_F + o) * IN_F);
        #pragma unroll
        for (int i = 0; i < IN_F / 4; ++i) {
            float4 v = W4[i];
            wreg[4*i+0] = v.x; wreg[4*i+1] = v.y; wreg[4*i+2] = v.z; wreg[4*i+3] = v.w;
        }
    }
    const int nn4 = n_nodes >> 2;   // 25000
    for (int q = blockIdx.x; q < nn4; q += gridDim.x) {
        const int n0 = q << 2;
        if (t < 64) {
            float4 v = reinterpret_cast<const float4*>(feat + (size_t)n0 * IN_F)[t];
            reinterpret_cast<float4*>(frow[t >> 4])[t & 15] = v;
        }
        __syncthreads();
        const float4* f0 = reinterpret_cast<const float4*>(frow[0]);
        const float4* f1 = reinterpret_cast<const float4*>(frow[1]);
        const float4* f2 = reinterpret_cast<const float4*>(frow[2]);
        const float4* f3 = reinterpret_cast<const float4*>(frow[3]);
        float a0 = 0.f, a1 = 0.f, a2 = 0.f, a3 = 0.f;
        #pragma unroll
        for (int i = 0; i < IN_F / 4; ++i) {
            const float4 v0 = f0[i], v1 = f1[i], v2 = f2[i], v3 = f3[i];
            const float w0 = wreg[4*i], w1 = wreg[4*i+1], w2 = wreg[4*i+2], w3 = wreg[4*i+3];
            a0 = fmaf(v0.x,w0, fmaf(v0.y,w1, fmaf(v0.z,w2, fmaf(v0.w,w3, a0))));
            a1 = fmaf(v1.x,w0, fmaf(v1.y,w1, fmaf(v1.z,w2, fmaf(v1.w,w3, a1))));
            a2 = fmaf(v2.x,w0, fmaf(v2.y,w1, fmaf(v2.z,w2, fmaf(v2.w,w3, a2))));
            a3 = fmaf(v3.x,w0, fmaf(v3.y,w1, fmaf(v3.z,w2, fmaf(v3.w,w3, a3))));
        }
        hb[(size_t)(n0+0) * 256 + t] = (unsigned short)f2bf(a0);
        hb[(size_t)(n0+1) * 256 + t] = (unsigned short)f2bf(a1);
        hb[(size_t)(n0+2) * 256 + t] = (unsigned short)f2bf(a2);
        hb[(size_t)(n0+3) * 256 + t] = (unsigned short)f2bf(a3);
        __syncthreads();
    }
}

// ---------------------------------------------------------------------------
// scan1: per-block sums of cnt
// ---------------------------------------------------------------------------
__global__ __launch_bounds__(256) void scan1_kernel(
    const int* __restrict__ cnt, int* __restrict__ bsum)
{
    __shared__ int s[SCAN_BLK];
    int i = blockIdx.x * SCAN_BLK + threadIdx.x;
    int v = (i < N_NODES_C) ? cnt[i] : 0;
    s[threadIdx.x] = v; __syncthreads();
    for (int off = SCAN_BLK / 2; off > 0; off >>= 1) {
        if (threadIdx.x < off) s[threadIdx.x] += s[threadIdx.x + off];
        __syncthreads();
    }
    if (threadIdx.x == 0) bsum[blockIdx.x] = s[0];
}

// ---------------------------------------------------------------------------
// scan23: block-prefix over bsum + local exclusive scan -> row_start,
// padded cursor (one counter per 64B line)
// ---------------------------------------------------------------------------
__global__ __launch_bounds__(256) void scan23_kernel(
    const int* __restrict__ cnt, const int* __restrict__ bsum,
    int* __restrict__ row_start, int* __restrict__ cursor_pad)
{
    __shared__ int pre[SCAN_BLK];
    __shared__ int s[SCAN_BLK];
    const int t = threadIdx.x;
    int p = 0;
    for (int i = t; i < (int)blockIdx.x; i += SCAN_BLK) p += bsum[i];
    pre[t] = p; __syncthreads();
    for (int off = SCAN_BLK / 2; off > 0; off >>= 1) {
        if (t < off) pre[t] += pre[t + off];
        __syncthreads();
    }
    const int boff = pre[0];
    const int i = blockIdx.x * SCAN_BLK + t;
    int v = (i < N_NODES_C) ? cnt[i] : 0;
    s[t] = v; __syncthreads();
    for (int off = 1; off < SCAN_BLK; off <<= 1) {
        int x = (t >= off) ? s[t - off] : 0;
        __syncthreads();
        s[t] += x;
        __syncthreads();
    }
    if (i < N_NODES_C) {
        int ex = s[t] - v + boff;
        row_start[i] = ex;
        cursor_pad[(size_t)i * CPAD] = ex;
        if (i == N_NODES_C - 1) row_start[N_NODES_C] = ex + v;
    }
}

// ---------------------------------------------------------------------------
// scatter (gauss fused, XCD-sliced): block b handles dst-slice b&7; computes
// g for matching lanes, cursor atomic + 16B rec store stay XCD-local.
// ---------------------------------------------------------------------------
__global__ __launch_bounds__(256) void scatter_kernel(
    const int* __restrict__ src, const int* __restrict__ dst,
    const float* __restrict__ pseudo, const float* __restrict__ mu,
    const float* __restrict__ inv_sigma, int* __restrict__ cursor_pad,
    uint4* __restrict__ rec)
{
    float mm[NK*3], ss[NK*3];
    #pragma unroll
    for (int i = 0; i < NK*3; ++i) { mm[i] = mu[i]; ss[i] = inv_sigma[i]; }
    const int slice = (int)blockIdx.x & 7;
    const int w     = (int)blockIdx.x >> 3;          // 0..255 within slice
    const int lo = slice * SLICE_N, hi = lo + SLICE_N;
    for (int c = w; c < EBLK; c += SCAT_GRID / NSLICE) {
        const int e = c * 256 + (int)threadIdx.x;
        const int d = dst[e];
        if (d >= lo && d < hi) {
            const float p0 = pseudo[(size_t)e * 3 + 0];
            const float p1 = pseudo[(size_t)e * 3 + 1];
            const float p2 = pseudo[(size_t)e * 3 + 2];
            float g[NK];
            #pragma unroll
            for (int k = 0; k < NK; ++k) {
                const float d0 = p0 - mm[k*3+0], d1 = p1 - mm[k*3+1], d2 = p2 - mm[k*3+2];
                const float s0 = ss[k*3+0], s1 = ss[k*3+1], s2 = ss[k*3+2];
                g[k] = __expf(-0.5f * (d0*d0*s0*s0 + d1*d1*s1*s1 + d2*d2*s2*s2));
            }
            const int pos = atomicAdd(&cursor_pad[(size_t)d * CPAD], 1);
            uint4 r;
            r.x = (unsigned int)src[e];
            r.y = f2bf(g[0]) | (f2bf(g[1]) << 16);
            r.z = f2bf(g[2]) | (f2bf(g[3]) << 16);
            r.w = 0u;
            rec[pos] = r;
        }
    }
}

// ---------------------------------------------------------------------------
// gather: one wave per dst node (pipelined; at structural floor:
// 400MB L2-miss traffic mandatory = 8 XCD x 51.2MB hb at ~3.65 TB/s fabric)
// ---------------------------------------------------------------------------
__global__ __launch_bounds__(256, 2) void gather_kernel(
    const int* __restrict__ row_start, const uint4* __restrict__ rec,
    const unsigned short* __restrict__ hb,
    const float* __restrict__ feat, const float* __restrict__ bias,
    float* __restrict__ out, int n_nodes)
{
    const int lane = threadIdx.x & 63;
    const int v = (blockIdx.x * 256 + threadIdx.x) >> 6;
    if (v >= n_nodes) return;
    const int r0 = row_start[v];
    const int r1 = row_start[v + 1];
    float acc = 0.f;
    int j = r0;
    const int jend4 = r0 + ((r1 - r0) & ~3);
    if (j < jend4) {
        uint4 a0 = rec[j+0], a1 = rec[j+1], a2 = rec[j+2], a3 = rec[j+3];
        j += 4;
        for (; j < jend4; j += 4) {
            const uint2 h0 = *(const uint2*)(hb + (size_t)a0.x * 256 + lane * 4);
            const uint2 h1 = *(const uint2*)(hb + (size_t)a1.x * 256 + lane * 4);
            const uint2 h2 = *(const uint2*)(hb + (size_t)a2.x * 256 + lane * 4);
            const uint2 h3 = *(const uint2*)(hb + (size_t)a3.x * 256 + lane * 4);
            const uint4 b0 = rec[j+0], b1 = rec[j+1], b2 = rec[j+2], b3 = rec[j+3];
            acc += bflo(a0.y)*bflo(h0.x) + bfhi(a0.y)*bfhi(h0.x)
                 + bflo(a0.z)*bflo(h0.y) + bfhi(a0.z)*bfhi(h0.y);
            acc += bflo(a1.y)*bflo(h1.x) + bfhi(a1.y)*bfhi(h1.x)
                 + bflo(a1.z)*bflo(h1.y) + bfhi(a1.z)*bfhi(h1.y);
            acc += bflo(a2.y)*bflo(h2.x) + bfhi(a2.y)*bfhi(h2.x)
                 + bflo(a2.z)*bflo(h2.y) + bfhi(a2.z)*bfhi(h2.y);
            acc += bflo(a3.y)*bflo(h3.x) + bfhi(a3.y)*bfhi(h3.x)
                 + bflo(a3.z)*bflo(h3.y) + bfhi(a3.z)*bfhi(h3.y);
            a0 = b0; a1 = b1; a2 = b2; a3 = b3;
        }
        {
            const uint2 h0 = *(const uint2*)(hb + (size_t)a0.x * 256 + lane * 4);
            const uint2 h1 = *(const uint2*)(hb + (size_t)a1.x * 256 + lane * 4);
            const uint2 h2 = *(const uint2*)(hb + (size_t)a2.x * 256 + lane * 4);
            const uint2 h3 = *(const uint2*)(hb + (size_t)a3.x * 256 + lane * 4);
            acc += bflo(a0.y)*bflo(h0.x) + bfhi(a0.y)*bfhi(h0.x)
                 + bflo(a0.z)*bflo(h0.y) + bfhi(a0.z)*bfhi(h0.y);
            acc += bflo(a1.y)*bflo(h1.x) + bfhi(a1.y)*bfhi(h1.x)
                 + bflo(a1.z)*bflo(h1.y) + bfhi(a1.z)*bfhi(h1.y);
            acc += bflo(a2.y)*bflo(h2.x) + bfhi(a2.y)*bfhi(h2.x)
                 + bflo(a2.z)*bflo(h2.y) + bfhi(a2.z)*bfhi(h2.y);
            acc += bflo(a3.y)*bflo(h3.x) + bfhi(a3.y)*bfhi(h3.x)
                 + bflo(a3.z)*bflo(h3.y) + bfhi(a3.z)*bfhi(h3.y);
        }
    }
    for (; j < r1; ++j) {
        const uint4 ra = rec[j];
        const uint2 ha = *(const uint2*)(hb + (size_t)ra.x * 256 + lane * 4);
        acc += bflo(ra.y)*bflo(ha.x) + bfhi(ra.y)*bfhi(ha.x)
             + bflo(ra.z)*bflo(ha.y) + bfhi(ra.z)*bfhi(ha.y);
    }
    out[(size_t)v * OUT_F + lane] = acc + feat[(size_t)v * OUT_F + lane] + bias[lane];
}

extern "C" void kernel_launch(void* const* d_in, const int* in_sizes, int n_in,
                              void* d_out, int out_size, void* d_ws, size_t ws_size,
                              hipStream_t stream) {
    const float* feat      = (const float*)d_in[0];
    const float* pseudo    = (const float*)d_in[1];
    const int*   src       = (const int*)d_in[2];
    const int*   dst       = (const int*)d_in[3];
    const float* W_fc      = (const float*)d_in[4];
    const float* mu        = (const float*)d_in[5];
    const float* inv_sigma = (const float*)d_in[6];
    const float* bias      = (const float*)d_in[7];
    float* out = (float*)d_out;

    char* ws = (char*)d_ws;
    unsigned short* hb = (unsigned short*)ws;  ws += (size_t)N_NODES_C * 256 * 2;     // 51.2 MB
    uint4* rec         = (uint4*)ws;           ws += (size_t)N_EDGES_C * 16;          // 25.6 MB
    int* cursor_pad    = (int*)ws;             ws += (size_t)N_NODES_C * CPAD * 4;    // 6.4 MB
    int* cnt           = (int*)ws;             ws += (size_t)N_NODES_C * 4;           // 0.4 MB
    int* row_start     = (int*)ws;             ws += (size_t)(N_NODES_C + 4) * 4;     // 0.4 MB
    int* bsum          = (int*)ws;             ws += 512 * 4;

    hipMemsetAsync(cnt, 0, (size_t)N_NODES_C * 4, stream);
    proj_hist_kernel<<<SCAT_GRID, 256, 0, stream>>>(dst, cnt, feat, W_fc, hb, N_NODES_C);
    scan1_kernel<<<NBLK, SCAN_BLK, 0, stream>>>(cnt, bsum);
    scan23_kernel<<<NBLK, SCAN_BLK, 0, stream>>>(cnt, bsum, row_start, cursor_pad);
    scatter_kernel<<<SCAT_GRID, 256, 0, stream>>>(src, dst, pseudo, mu, inv_sigma,
                                                  cursor_pad, rec);
    gather_kernel<<<(N_NODES_C * 64 + 255) / 256, 256, 0, stream>>>(
        row_start, rec, hb, feat, bias, out, N_NODES_C);
}